// Round 3
// baseline (57.526 us; speedup 1.0000x reference)
//
#include <hip/hip_runtime.h>
#include <hip/hip_bf16.h>

// AlignmentLoss: loss = -(sum(tril(G,-1)*eq) / (sum(tril(eq,-1)) * ||tril(G,-1)||_F))
// with G = A A^T, A: 4096x1024 fp32, target: 4096 int32 (classes < 1000).
//
//   S1 = 0.5*(sum_c ||s_c||^2 - sum_i ||a_i||^2)   (exact fp32/fp64 path)
//   S2 = 0.5*(sum_c n_c^2 - N)
//   S3 = sum_{i>j} g_ij^2  -- lower-triangle 128x128 tiles of G = A A^T in
//        bf16 MFMA, K=1024 along A's natural layout, fused masked Frobenius.
//   loss = -S1 / (S2 * sqrt(S3))
//
// R3 change (isolated): kfrob K-loop is now the T3 minimum 2-phase pipeline —
// double-buffered LDS, STAGE(next) issued BEFORE compute(cur), one barrier
// per K-step, so global->LDS latency hides under the MFMA phase.

typedef __attribute__((ext_vector_type(8))) short short8;
typedef __attribute__((ext_vector_type(4))) float f32x4;

#define N_ROWS 4096
#define D_DIM  1024
#define N_CLS  1000
#define NTILE  32          // 4096 / 128 block-rows
#define NBLK   528         // NTILE*(NTILE+1)/2 lower-triangle tiles
#define NK     32          // 1024 / BK,  BK = 32

__device__ __forceinline__ unsigned short f2bf(float f) {
  unsigned u = __float_as_uint(f);
  u += 0x7fffu + ((u >> 16) & 1u);   // round-to-nearest-even
  return (unsigned short)(u >> 16);
}

__device__ __forceinline__ void gload16(const short* g, const char* l) {
  __builtin_amdgcn_global_load_lds(
      (const __attribute__((address_space(1))) unsigned*)g,
      (__attribute__((address_space(3))) unsigned*)(void*)l, 16, 0, 0);
}

// ---------------------------------------------------------------------------
// kconvrow: A fp32 -> Ab bf16 (same layout) + per-block fp64 partial of
// sum_i ||a_i||^2.  512 blocks x 256 thr; wave handles 2 rows.
// ---------------------------------------------------------------------------
__global__ void __launch_bounds__(256) kconvrow(const float* __restrict__ A,
                                                short* __restrict__ Ab,
                                                double* __restrict__ rowp) {
  __shared__ double wr2[4];
  const int tid = threadIdx.x, lane = tid & 63, w = tid >> 6;
  const int row0 = blockIdx.x * 8;
  double ls = 0.0;
#pragma unroll
  for (int rr = 0; rr < 2; ++rr) {
    const int i = row0 + w * 2 + rr;
    const float4* src = (const float4*)(A + (size_t)i * D_DIM);
    short4* dst = (short4*)(Ab + (size_t)i * D_DIM);
    float s = 0.f;
#pragma unroll
    for (int c = 0; c < 4; ++c) {
      const float4 v = src[lane + c * 64];
      s += v.x * v.x + v.y * v.y + v.z * v.z + v.w * v.w;
      short4 o;
      o.x = (short)f2bf(v.x); o.y = (short)f2bf(v.y);
      o.z = (short)f2bf(v.z); o.w = (short)f2bf(v.w);
      dst[lane + c * 64] = o;
    }
#pragma unroll
    for (int off = 32; off; off >>= 1) s += __shfl_down(s, off);
    if (lane == 0) ls += (double)s;
  }
  if (lane == 0) wr2[w] = ls;
  __syncthreads();
  if (tid == 0) rowp[blockIdx.x] = wr2[0] + wr2[1] + wr2[2] + wr2[3];
}

// ---------------------------------------------------------------------------
// kclass: block per class; LDS list of matching rows; s_c in registers
// (thread owns 4 dims); emits ||s_c||^2 (fp64) and n_c.  Exact fp32 path.
// ---------------------------------------------------------------------------
__global__ void __launch_bounds__(256) kclass(const float* __restrict__ A,
                                              const int* __restrict__ target,
                                              double* __restrict__ cssp,
                                              int* __restrict__ cntp) {
  __shared__ int list[N_ROWS];
  __shared__ int lcnt;
  __shared__ float wred[4];
  const int c = blockIdx.x, tid = threadIdx.x;
  if (tid == 0) lcnt = 0;
  __syncthreads();
  for (int j = tid; j < N_ROWS; j += 256)
    if (target[j] == c) { int p = atomicAdd(&lcnt, 1); list[p] = j; }
  __syncthreads();
  const int n = lcnt;
  float4 acc = make_float4(0.f, 0.f, 0.f, 0.f);
  for (int m = 0; m < n; ++m) {
    const float4 v = *(const float4*)(A + (size_t)list[m] * D_DIM + tid * 4);
    acc.x += v.x; acc.y += v.y; acc.z += v.z; acc.w += v.w;
  }
  float s = acc.x * acc.x + acc.y * acc.y + acc.z * acc.z + acc.w * acc.w;
#pragma unroll
  for (int off = 32; off; off >>= 1) s += __shfl_down(s, off);
  const int lane = tid & 63, wid = tid >> 6;
  if (lane == 0) wred[wid] = s;
  __syncthreads();
  if (tid == 0) {
    cssp[c] = (double)(wred[0] + wred[1] + wred[2] + wred[3]);
    cntp[c] = n;
  }
}

// ---------------------------------------------------------------------------
// kfrob: lower-triangle 128x128 tiles of G = Ab*Ab^T, bf16 MFMA, 2-phase
// double-buffered pipeline, fused masked-Frobenius reduce.  Grid NBLK=528.
// ---------------------------------------------------------------------------
__global__ void __launch_bounds__(256) kfrob(const short* __restrict__ Ab,
                                             double* __restrict__ frobp) {
  __shared__ __align__(16) short As[2][128 * 32];   // 2 x 8 KB
  __shared__ __align__(16) short Bs[2][128 * 32];   // 2 x 8 KB
  __shared__ double wred[4];
  const int tid = threadIdx.x, lane = tid & 63, w = tid >> 6;

  // decode lower-triangle pair: b = bi*(bi+1)/2 + bj, bj <= bi
  const int b = blockIdx.x;
  int bi = (int)((sqrtf(8.f * (float)b + 1.f) - 1.f) * 0.5f);
  while ((bi + 1) * (bi + 2) / 2 <= b) ++bi;
  while (bi * (bi + 1) / 2 > b) --bi;
  const int bj = b - bi * (bi + 1) / 2;
  const bool diag = (bi == bj);

  const short* Pa = Ab + (size_t)(bi * 128) * D_DIM;
  const short* Pb = Ab + (size_t)(bj * 128) * D_DIM;

  f32x4 acc[4][4];
#pragma unroll
  for (int m = 0; m < 4; ++m)
#pragma unroll
    for (int n = 0; n < 4; ++n) acc[m][n] = (f32x4){0.f, 0.f, 0.f, 0.f};

  const int wr = w >> 1, wc = w & 1;
  const int row16 = lane & 15, ko = (lane >> 4) * 8;
  const int sr = tid >> 2, sc = tid & 3;          // staging row / 8-short chunk

  // per-thread global offsets for staging (row sr and sr+64, chunk sc)
  const size_t g0 = (size_t)sr * D_DIM + sc * 8;
  const size_t g1 = (size_t)(sr + 64) * D_DIM + sc * 8;
  const int l0 = w * 1024;                         // wave-uniform LDS byte base
  const int l1 = 4096 + w * 1024;

#define STAGE(buf, k0)                                                      \
  do {                                                                      \
    gload16(Pa + g0 + (k0), (const char*)As[buf] + l0);                     \
    gload16(Pb + g0 + (k0), (const char*)Bs[buf] + l0);                     \
    gload16(Pa + g1 + (k0), (const char*)As[buf] + l1);                     \
    gload16(Pb + g1 + (k0), (const char*)Bs[buf] + l1);                     \
  } while (0)

#define COMPUTE(buf)                                                        \
  do {                                                                      \
    short8 af[4], bf[4];                                                    \
    _Pragma("unroll")                                                       \
    for (int m = 0; m < 4; ++m)                                             \
      af[m] = *(const short8*)&As[buf][(wr * 64 + m * 16 + row16) * 32 + ko];\
    _Pragma("unroll")                                                       \
    for (int n = 0; n < 4; ++n)                                             \
      bf[n] = *(const short8*)&Bs[buf][(wc * 64 + n * 16 + row16) * 32 + ko];\
    _Pragma("unroll")                                                       \
    for (int m = 0; m < 4; ++m)                                             \
      _Pragma("unroll")                                                     \
      for (int n = 0; n < 4; ++n)                                           \
        acc[m][n] = __builtin_amdgcn_mfma_f32_16x16x32_bf16(af[m], bf[n],   \
                                                            acc[m][n], 0, 0, 0);\
  } while (0)

  // prologue: stage tile 0
  STAGE(0, 0);
  __syncthreads();                 // drains vmcnt before barrier
  int cur = 0;
#pragma unroll 1
  for (int t = 0; t < NK - 1; ++t) {
    STAGE(cur ^ 1, (t + 1) * 32);  // prefetch next tile into other buffer
    COMPUTE(cur);                  // ds_read + 16 MFMA on current tile
    __syncthreads();               // vmcnt(0)+lgkmcnt(0) drain: prefetch done
    cur ^= 1;
  }
  COMPUTE(cur);                    // epilogue tile (no prefetch)
#undef STAGE
#undef COMPUTE

  float fs = 0.f;
  if (!diag) {
#pragma unroll
    for (int m = 0; m < 4; ++m)
#pragma unroll
      for (int n = 0; n < 4; ++n)
#pragma unroll
        for (int q = 0; q < 4; ++q) fs += acc[m][n][q] * acc[m][n][q];
  } else {
    const int rbase = (lane >> 4) * 4, cbase = lane & 15;
#pragma unroll
    for (int m = 0; m < 4; ++m)
#pragma unroll
      for (int n = 0; n < 4; ++n)
#pragma unroll
        for (int q = 0; q < 4; ++q) {
          const int rl = wr * 64 + m * 16 + rbase + q;
          const int cl = wc * 64 + n * 16 + cbase;
          if (rl > cl) fs += acc[m][n][q] * acc[m][n][q];
        }
  }
#pragma unroll
  for (int off = 32; off; off >>= 1) fs += __shfl_down(fs, off);
  if (lane == 0) wred[w] = (double)fs;
  __syncthreads();
  if (tid == 0)
    frobp[b] = wred[0] + wred[1] + wred[2] + wred[3];
}

// ---------------------------------------------------------------------------
// kfinal: fp64 reduce + scalar math.
// ---------------------------------------------------------------------------
__global__ void __launch_bounds__(256) kfinal(const double* __restrict__ rowp,
                                              const double* __restrict__ cssp,
                                              const int* __restrict__ cntp,
                                              const double* __restrict__ frobp,
                                              float* __restrict__ out) {
  __shared__ double red[256];
  const int tid = threadIdx.x;
  double lsum = rowp[tid] + rowp[tid + 256];
  double lcss = 0.0, lcnn = 0.0, lfr = 0.0;
  for (int c = tid; c < N_CLS; c += 256) {
    lcss += cssp[c];
    const double nc = (double)cntp[c];
    lcnn += nc * nc;
  }
  for (int c = tid; c < NBLK; c += 256) lfr += frobp[c];

  double vals[4] = {lsum, lcss, lcnn, lfr};
  double res[4];
  for (int v = 0; v < 4; ++v) {
    red[tid] = vals[v];
    __syncthreads();
    for (int s = 128; s; s >>= 1) {
      if (tid < s) red[tid] += red[tid + s];
      __syncthreads();
    }
    res[v] = red[0];
    __syncthreads();
  }
  if (tid == 0) {
    const double sumr = res[0], css = res[1], cnn = res[2], frob = res[3];
    const double S1 = 0.5 * (css - sumr);
    const double S2 = 0.5 * (cnn - (double)N_ROWS);
    const double S3 = frob;
    out[0] = (float)(-(S1 / (S2 * sqrt(S3))));
  }
}

extern "C" void kernel_launch(void* const* d_in, const int* in_sizes, int n_in,
                              void* d_out, int out_size, void* d_ws, size_t ws_size,
                              hipStream_t stream) {
  const float* A = (const float*)d_in[0];
  const int* target = (const int*)d_in[1];
  float* out = (float*)d_out;

  char* ws = (char*)d_ws;
  short*  Ab    = (short*)ws;                                   // 8,388,608 B
  double* rowp  = (double*)(ws + 8388608);                      // 512 doubles
  double* cssp  = (double*)(ws + 8388608 + 4096);               // 1000 doubles
  int*    cntp  = (int*)   (ws + 8388608 + 4096 + 8000);        // 1000 ints (pad 4096)
  double* frobp = (double*)(ws + 8388608 + 4096 + 8000 + 4096); // 528 doubles

  kconvrow<<<512, 256, 0, stream>>>(A, Ab, rowp);
  kclass<<<N_CLS, 256, 0, stream>>>(A, target, cssp, cntp);
  kfrob<<<NBLK, 256, 0, stream>>>(Ab, frobp);
  kfinal<<<1, 256, 0, stream>>>(rowp, cssp, cntp, frobp, out);
}

// Round 4
// 52.825 us; speedup vs baseline: 1.0890x; 1.0890x over previous
//
#include <hip/hip_runtime.h>
#include <hip/hip_bf16.h>

// AlignmentLoss: loss = -(sum(tril(G,-1)*eq) / (sum(tril(eq,-1)) * ||tril(G,-1)||_F))
// with G = A A^T, A: 4096x1024 fp32, target: 4096 int32 (classes < 1000).
//
//   S1 = 0.5*(sum_c ||s_c||^2 - sum_i ||a_i||^2)   (exact fp32/fp64 path)
//   S2 = 0.5*(sum_c n_c^2 - N)
//   S3 = sum_{i>j} g_ij^2  -- lower-triangle 128x128 tiles of G = A A^T in
//        bf16 MFMA, K=1024 along A's natural layout, fused masked Frobenius.
//   loss = -S1 / (S2 * sqrt(S3))
//
// R4 change (isolated, R3's dbuf reverted): kfrob goes 4 -> 8 waves per block
// (512 threads, wave grid 2x4, 64x32 per wave). Same grid (528), same LDS
// (16.5 KB), same traffic; doubles waves/CU to ~16 so cross-wave overlap
// hides the per-K-step stage latency (m103 ran 16 waves/CU at 912 TF).

typedef __attribute__((ext_vector_type(8))) short short8;
typedef __attribute__((ext_vector_type(4))) float f32x4;

#define N_ROWS 4096
#define D_DIM  1024
#define N_CLS  1000
#define NTILE  32          // 4096 / 128 block-rows
#define NBLK   528         // NTILE*(NTILE+1)/2 lower-triangle tiles
#define NK     32          // 1024 / BK,  BK = 32

__device__ __forceinline__ unsigned short f2bf(float f) {
  unsigned u = __float_as_uint(f);
  u += 0x7fffu + ((u >> 16) & 1u);   // round-to-nearest-even
  return (unsigned short)(u >> 16);
}

__device__ __forceinline__ void gload16(const short* g, const char* l) {
  __builtin_amdgcn_global_load_lds(
      (const __attribute__((address_space(1))) unsigned*)g,
      (__attribute__((address_space(3))) unsigned*)(void*)l, 16, 0, 0);
}

// ---------------------------------------------------------------------------
// kconvrow: A fp32 -> Ab bf16 (same layout) + per-block fp64 partial of
// sum_i ||a_i||^2.  512 blocks x 256 thr; wave handles 2 rows.
// ---------------------------------------------------------------------------
__global__ void __launch_bounds__(256) kconvrow(const float* __restrict__ A,
                                                short* __restrict__ Ab,
                                                double* __restrict__ rowp) {
  __shared__ double wr2[4];
  const int tid = threadIdx.x, lane = tid & 63, w = tid >> 6;
  const int row0 = blockIdx.x * 8;
  double ls = 0.0;
#pragma unroll
  for (int rr = 0; rr < 2; ++rr) {
    const int i = row0 + w * 2 + rr;
    const float4* src = (const float4*)(A + (size_t)i * D_DIM);
    short4* dst = (short4*)(Ab + (size_t)i * D_DIM);
    float s = 0.f;
#pragma unroll
    for (int c = 0; c < 4; ++c) {
      const float4 v = src[lane + c * 64];
      s += v.x * v.x + v.y * v.y + v.z * v.z + v.w * v.w;
      short4 o;
      o.x = (short)f2bf(v.x); o.y = (short)f2bf(v.y);
      o.z = (short)f2bf(v.z); o.w = (short)f2bf(v.w);
      dst[lane + c * 64] = o;
    }
#pragma unroll
    for (int off = 32; off; off >>= 1) s += __shfl_down(s, off);
    if (lane == 0) ls += (double)s;
  }
  if (lane == 0) wr2[w] = ls;
  __syncthreads();
  if (tid == 0) rowp[blockIdx.x] = wr2[0] + wr2[1] + wr2[2] + wr2[3];
}

// ---------------------------------------------------------------------------
// kclass: block per class; LDS list of matching rows; s_c in registers
// (thread owns 4 dims); emits ||s_c||^2 (fp64) and n_c.  Exact fp32 path.
// ---------------------------------------------------------------------------
__global__ void __launch_bounds__(256) kclass(const float* __restrict__ A,
                                              const int* __restrict__ target,
                                              double* __restrict__ cssp,
                                              int* __restrict__ cntp) {
  __shared__ int list[N_ROWS];
  __shared__ int lcnt;
  __shared__ float wred[4];
  const int c = blockIdx.x, tid = threadIdx.x;
  if (tid == 0) lcnt = 0;
  __syncthreads();
  for (int j = tid; j < N_ROWS; j += 256)
    if (target[j] == c) { int p = atomicAdd(&lcnt, 1); list[p] = j; }
  __syncthreads();
  const int n = lcnt;
  float4 acc = make_float4(0.f, 0.f, 0.f, 0.f);
  for (int m = 0; m < n; ++m) {
    const float4 v = *(const float4*)(A + (size_t)list[m] * D_DIM + tid * 4);
    acc.x += v.x; acc.y += v.y; acc.z += v.z; acc.w += v.w;
  }
  float s = acc.x * acc.x + acc.y * acc.y + acc.z * acc.z + acc.w * acc.w;
#pragma unroll
  for (int off = 32; off; off >>= 1) s += __shfl_down(s, off);
  const int lane = tid & 63, wid = tid >> 6;
  if (lane == 0) wred[wid] = s;
  __syncthreads();
  if (tid == 0) {
    cssp[c] = (double)(wred[0] + wred[1] + wred[2] + wred[3]);
    cntp[c] = n;
  }
}

// ---------------------------------------------------------------------------
// kfrob: lower-triangle 128x128 tiles of G = Ab*Ab^T, bf16 MFMA, single-
// buffer 2-barrier loop, 8 waves (2x4, 64x32 per wave), fused masked
// Frobenius.  Grid NBLK=528 x 512 threads.
// ---------------------------------------------------------------------------
__global__ void __launch_bounds__(512, 4) kfrob(const short* __restrict__ Ab,
                                                double* __restrict__ frobp) {
  __shared__ __align__(16) short As[128 * 32];   // 8 KB
  __shared__ __align__(16) short Bs[128 * 32];   // 8 KB
  __shared__ double wred[8];
  const int tid = threadIdx.x, lane = tid & 63, w = tid >> 6;

  // decode lower-triangle pair: b = bi*(bi+1)/2 + bj, bj <= bi
  const int b = blockIdx.x;
  int bi = (int)((sqrtf(8.f * (float)b + 1.f) - 1.f) * 0.5f);
  while ((bi + 1) * (bi + 2) / 2 <= b) ++bi;
  while (bi * (bi + 1) / 2 > b) --bi;
  const int bj = b - bi * (bi + 1) / 2;
  const bool diag = (bi == bj);

  const short* Pa = Ab + (size_t)(bi * 128) * D_DIM;
  const short* Pb = Ab + (size_t)(bj * 128) * D_DIM;

  f32x4 acc[4][2];
#pragma unroll
  for (int m = 0; m < 4; ++m)
#pragma unroll
    for (int n = 0; n < 2; ++n) acc[m][n] = (f32x4){0.f, 0.f, 0.f, 0.f};

  const int wr = w >> 2, wc = w & 3;             // wave tile: rows 64*wr, cols 32*wc
  const int row16 = lane & 15, ko = (lane >> 4) * 8;

  // staging: 512 thr x 16B = 8KB = one full [128][32]-short buffer per issue.
  // thread t -> row t>>2, chunk t&3; LDS offset = t*16 (linear, wave-uniform
  // base + lane*16 as global_load_lds requires).
  const int sr = tid >> 2, sc = tid & 3;
  const size_t gofs = (size_t)sr * D_DIM + sc * 8;
  const int lofs = w * 1024;                     // = tid*16 - lane*16

  for (int k0 = 0; k0 < D_DIM; k0 += 32) {
    gload16(Pa + gofs + k0, (const char*)As + lofs);
    gload16(Pb + gofs + k0, (const char*)Bs + lofs);
    __syncthreads();
    short8 af[4], bf[2];
#pragma unroll
    for (int m = 0; m < 4; ++m)
      af[m] = *(const short8*)&As[(wr * 64 + m * 16 + row16) * 32 + ko];
#pragma unroll
    for (int n = 0; n < 2; ++n)
      bf[n] = *(const short8*)&Bs[(wc * 32 + n * 16 + row16) * 32 + ko];
#pragma unroll
    for (int m = 0; m < 4; ++m)
#pragma unroll
      for (int n = 0; n < 2; ++n)
        acc[m][n] = __builtin_amdgcn_mfma_f32_16x16x32_bf16(af[m], bf[n], acc[m][n], 0, 0, 0);
    __syncthreads();
  }

  float fs = 0.f;
  if (!diag) {
#pragma unroll
    for (int m = 0; m < 4; ++m)
#pragma unroll
      for (int n = 0; n < 2; ++n)
#pragma unroll
        for (int q = 0; q < 4; ++q) fs += acc[m][n][q] * acc[m][n][q];
  } else {
    const int rbase = (lane >> 4) * 4, cbase = lane & 15;
#pragma unroll
    for (int m = 0; m < 4; ++m)
#pragma unroll
      for (int n = 0; n < 2; ++n)
#pragma unroll
        for (int q = 0; q < 4; ++q) {
          const int rl = wr * 64 + m * 16 + rbase + q;
          const int cl = wc * 32 + n * 16 + cbase;
          if (rl > cl) fs += acc[m][n][q] * acc[m][n][q];
        }
  }
#pragma unroll
  for (int off = 32; off; off >>= 1) fs += __shfl_down(fs, off);
  if (lane == 0) wred[w] = (double)fs;
  __syncthreads();
  if (tid == 0) {
    double t = 0.0;
#pragma unroll
    for (int i = 0; i < 8; ++i) t += wred[i];
    frobp[b] = t;
  }
}

// ---------------------------------------------------------------------------
// kfinal: fp64 reduce + scalar math.
// ---------------------------------------------------------------------------
__global__ void __launch_bounds__(256) kfinal(const double* __restrict__ rowp,
                                              const double* __restrict__ cssp,
                                              const int* __restrict__ cntp,
                                              const double* __restrict__ frobp,
                                              float* __restrict__ out) {
  __shared__ double red[256];
  const int tid = threadIdx.x;
  double lsum = rowp[tid] + rowp[tid + 256];
  double lcss = 0.0, lcnn = 0.0, lfr = 0.0;
  for (int c = tid; c < N_CLS; c += 256) {
    lcss += cssp[c];
    const double nc = (double)cntp[c];
    lcnn += nc * nc;
  }
  for (int c = tid; c < NBLK; c += 256) lfr += frobp[c];

  double vals[4] = {lsum, lcss, lcnn, lfr};
  double res[4];
  for (int v = 0; v < 4; ++v) {
    red[tid] = vals[v];
    __syncthreads();
    for (int s = 128; s; s >>= 1) {
      if (tid < s) red[tid] += red[tid + s];
      __syncthreads();
    }
    res[v] = red[0];
    __syncthreads();
  }
  if (tid == 0) {
    const double sumr = res[0], css = res[1], cnn = res[2], frob = res[3];
    const double S1 = 0.5 * (css - sumr);
    const double S2 = 0.5 * (cnn - (double)N_ROWS);
    const double S3 = frob;
    out[0] = (float)(-(S1 / (S2 * sqrt(S3))));
  }
}

extern "C" void kernel_launch(void* const* d_in, const int* in_sizes, int n_in,
                              void* d_out, int out_size, void* d_ws, size_t ws_size,
                              hipStream_t stream) {
  const float* A = (const float*)d_in[0];
  const int* target = (const int*)d_in[1];
  float* out = (float*)d_out;

  char* ws = (char*)d_ws;
  short*  Ab    = (short*)ws;                                   // 8,388,608 B
  double* rowp  = (double*)(ws + 8388608);                      // 512 doubles
  double* cssp  = (double*)(ws + 8388608 + 4096);               // 1000 doubles
  int*    cntp  = (int*)   (ws + 8388608 + 4096 + 8000);        // 1000 ints (pad 4096)
  double* frobp = (double*)(ws + 8388608 + 4096 + 8000 + 4096); // 528 doubles

  kconvrow<<<512, 256, 0, stream>>>(A, Ab, rowp);
  kclass<<<N_CLS, 256, 0, stream>>>(A, target, cssp, cntp);
  kfrob<<<NBLK, 512, 0, stream>>>(Ab, frobp);
  kfinal<<<1, 256, 0, stream>>>(rowp, cssp, cntp, frobp, out);
}

// Round 5
// 51.274 us; speedup vs baseline: 1.1219x; 1.0302x over previous
//
#include <hip/hip_runtime.h>
#include <hip/hip_bf16.h>

// AlignmentLoss: loss = -(sum(tril(G,-1)*eq) / (sum(tril(eq,-1)) * ||tril(G,-1)||_F))
// with G = A A^T, A: 4096x1024 fp32, target: 4096 int32 (classes < 1000).
//
//   S1 = 0.5*(sum_c ||s_c||^2 - sum_i ||a_i||^2)   (exact fp32/fp64 path)
//   S2 = 0.5*(sum_c n_c^2 - N)
//   S3 = sum_{i>j} g_ij^2  -- lower-triangle 128x128 tiles of G = A A^T in
//        bf16 MFMA, K=1024 along A's natural layout, fused masked Frobenius.
//   loss = -S1 / (S2 * sqrt(S3))
//
// R5 change (isolated vs R4): kfrob K-loop uses T3/T4 counted-vmcnt pipeline —
// LDS double-buffer, raw s_barrier (NOT __syncthreads), s_waitcnt vmcnt(2) so
// next tile's global_load_lds stay in flight across the compute phase.
// R3 failed because __syncthreads drains vmcnt(0) every step; this doesn't.

typedef __attribute__((ext_vector_type(8))) short short8;
typedef __attribute__((ext_vector_type(4))) float f32x4;

#define N_ROWS 4096
#define D_DIM  1024
#define N_CLS  1000
#define NTILE  32          // 4096 / 128 block-rows
#define NBLK   528         // NTILE*(NTILE+1)/2 lower-triangle tiles
#define NK     32          // 1024 / BK,  BK = 32

__device__ __forceinline__ unsigned short f2bf(float f) {
  unsigned u = __float_as_uint(f);
  u += 0x7fffu + ((u >> 16) & 1u);   // round-to-nearest-even
  return (unsigned short)(u >> 16);
}

__device__ __forceinline__ void gload16(const short* g, const char* l) {
  __builtin_amdgcn_global_load_lds(
      (const __attribute__((address_space(1))) unsigned*)g,
      (__attribute__((address_space(3))) unsigned*)(void*)l, 16, 0, 0);
}

// ---------------------------------------------------------------------------
// kconvrow: A fp32 -> Ab bf16 (same layout) + per-block fp64 partial of
// sum_i ||a_i||^2.  512 blocks x 256 thr; wave handles 2 rows.
// ---------------------------------------------------------------------------
__global__ void __launch_bounds__(256) kconvrow(const float* __restrict__ A,
                                                short* __restrict__ Ab,
                                                double* __restrict__ rowp) {
  __shared__ double wr2[4];
  const int tid = threadIdx.x, lane = tid & 63, w = tid >> 6;
  const int row0 = blockIdx.x * 8;
  double ls = 0.0;
#pragma unroll
  for (int rr = 0; rr < 2; ++rr) {
    const int i = row0 + w * 2 + rr;
    const float4* src = (const float4*)(A + (size_t)i * D_DIM);
    short4* dst = (short4*)(Ab + (size_t)i * D_DIM);
    float s = 0.f;
#pragma unroll
    for (int c = 0; c < 4; ++c) {
      const float4 v = src[lane + c * 64];
      s += v.x * v.x + v.y * v.y + v.z * v.z + v.w * v.w;
      short4 o;
      o.x = (short)f2bf(v.x); o.y = (short)f2bf(v.y);
      o.z = (short)f2bf(v.z); o.w = (short)f2bf(v.w);
      dst[lane + c * 64] = o;
    }
#pragma unroll
    for (int off = 32; off; off >>= 1) s += __shfl_down(s, off);
    if (lane == 0) ls += (double)s;
  }
  if (lane == 0) wr2[w] = ls;
  __syncthreads();
  if (tid == 0) rowp[blockIdx.x] = wr2[0] + wr2[1] + wr2[2] + wr2[3];
}

// ---------------------------------------------------------------------------
// kclass: block per class; LDS list of matching rows; s_c in registers
// (thread owns 4 dims); emits ||s_c||^2 (fp64) and n_c.  Exact fp32 path.
// ---------------------------------------------------------------------------
__global__ void __launch_bounds__(256) kclass(const float* __restrict__ A,
                                              const int* __restrict__ target,
                                              double* __restrict__ cssp,
                                              int* __restrict__ cntp) {
  __shared__ int list[N_ROWS];
  __shared__ int lcnt;
  __shared__ float wred[4];
  const int c = blockIdx.x, tid = threadIdx.x;
  if (tid == 0) lcnt = 0;
  __syncthreads();
  for (int j = tid; j < N_ROWS; j += 256)
    if (target[j] == c) { int p = atomicAdd(&lcnt, 1); list[p] = j; }
  __syncthreads();
  const int n = lcnt;
  float4 acc = make_float4(0.f, 0.f, 0.f, 0.f);
  for (int m = 0; m < n; ++m) {
    const float4 v = *(const float4*)(A + (size_t)list[m] * D_DIM + tid * 4);
    acc.x += v.x; acc.y += v.y; acc.z += v.z; acc.w += v.w;
  }
  float s = acc.x * acc.x + acc.y * acc.y + acc.z * acc.z + acc.w * acc.w;
#pragma unroll
  for (int off = 32; off; off >>= 1) s += __shfl_down(s, off);
  const int lane = tid & 63, wid = tid >> 6;
  if (lane == 0) wred[wid] = s;
  __syncthreads();
  if (tid == 0) {
    cssp[c] = (double)(wred[0] + wred[1] + wred[2] + wred[3]);
    cntp[c] = n;
  }
}

// ---------------------------------------------------------------------------
// kfrob: lower-triangle 128x128 tiles of G = Ab*Ab^T, bf16 MFMA, 8 waves
// (2x4, 64x32 per wave), LDS double-buffer + counted-vmcnt pipeline, fused
// masked Frobenius.  Grid NBLK=528 x 512 threads.
// ---------------------------------------------------------------------------
__global__ void __launch_bounds__(512, 4) kfrob(const short* __restrict__ Ab,
                                                double* __restrict__ frobp) {
  __shared__ __align__(16) short As[2][128 * 32];   // 2 x 8 KB
  __shared__ __align__(16) short Bs[2][128 * 32];   // 2 x 8 KB
  __shared__ double wred[8];
  const int tid = threadIdx.x, lane = tid & 63, w = tid >> 6;

  // decode lower-triangle pair: b = bi*(bi+1)/2 + bj, bj <= bi
  const int b = blockIdx.x;
  int bi = (int)((sqrtf(8.f * (float)b + 1.f) - 1.f) * 0.5f);
  while ((bi + 1) * (bi + 2) / 2 <= b) ++bi;
  while (bi * (bi + 1) / 2 > b) --bi;
  const int bj = b - bi * (bi + 1) / 2;
  const bool diag = (bi == bj);

  const short* Pa = Ab + (size_t)(bi * 128) * D_DIM;
  const short* Pb = Ab + (size_t)(bj * 128) * D_DIM;

  f32x4 acc[4][2];
#pragma unroll
  for (int m = 0; m < 4; ++m)
#pragma unroll
    for (int n = 0; n < 2; ++n) acc[m][n] = (f32x4){0.f, 0.f, 0.f, 0.f};

  const int wr = w >> 2, wc = w & 3;             // wave tile: rows 64*wr, cols 32*wc
  const int row16 = lane & 15, ko = (lane >> 4) * 8;

  // staging: 512 thr x 16B = 8KB = one full [128][32]-short buffer per issue.
  const int sr = tid >> 2, sc = tid & 3;
  const size_t gofs = (size_t)sr * D_DIM + sc * 8;
  const int lofs = w * 1024;                     // = tid*16 - lane*16 (linear)

#define STAGE(buf, k0)                                                      \
  do {                                                                      \
    gload16(Pa + gofs + (k0), (const char*)As[buf] + lofs);                 \
    gload16(Pb + gofs + (k0), (const char*)Bs[buf] + lofs);                 \
  } while (0)

#define COMPUTE(buf)                                                        \
  do {                                                                      \
    short8 af[4], bf[2];                                                    \
    _Pragma("unroll")                                                       \
    for (int m = 0; m < 4; ++m)                                             \
      af[m] = *(const short8*)&As[buf][(wr * 64 + m * 16 + row16) * 32 + ko];\
    _Pragma("unroll")                                                       \
    for (int n = 0; n < 2; ++n)                                             \
      bf[n] = *(const short8*)&Bs[buf][(wc * 32 + n * 16 + row16) * 32 + ko];\
    _Pragma("unroll")                                                       \
    for (int m = 0; m < 4; ++m)                                             \
      _Pragma("unroll")                                                     \
      for (int n = 0; n < 2; ++n)                                           \
        acc[m][n] = __builtin_amdgcn_mfma_f32_16x16x32_bf16(af[m], bf[n],   \
                                                            acc[m][n], 0, 0, 0);\
  } while (0)

  STAGE(0, 0);                       // prologue: tile 0 in flight
  int cur = 0;
#pragma unroll 1
  for (int t = 0; t < NK - 1; ++t) {
    STAGE(cur ^ 1, (t + 1) * 32);    // issue next tile (2 loads/thread)
    asm volatile("s_waitcnt vmcnt(2)" ::: "memory");   // wait tile t only
    __builtin_amdgcn_sched_barrier(0);
    __builtin_amdgcn_s_barrier();    // all waves: tile t resident
    __builtin_amdgcn_sched_barrier(0);
    COMPUTE(cur);
    asm volatile("s_waitcnt lgkmcnt(0)" ::: "memory"); // all ds_reads retired
    __builtin_amdgcn_sched_barrier(0);
    __builtin_amdgcn_s_barrier();    // safe to overwrite buf cur next iter
    __builtin_amdgcn_sched_barrier(0);
    cur ^= 1;
  }
  asm volatile("s_waitcnt vmcnt(0)" ::: "memory");     // last tile resident
  __builtin_amdgcn_sched_barrier(0);
  __builtin_amdgcn_s_barrier();
  __builtin_amdgcn_sched_barrier(0);
  COMPUTE(cur);
#undef STAGE
#undef COMPUTE

  float fs = 0.f;
  if (!diag) {
#pragma unroll
    for (int m = 0; m < 4; ++m)
#pragma unroll
      for (int n = 0; n < 2; ++n)
#pragma unroll
        for (int q = 0; q < 4; ++q) fs += acc[m][n][q] * acc[m][n][q];
  } else {
    const int rbase = (lane >> 4) * 4, cbase = lane & 15;
#pragma unroll
    for (int m = 0; m < 4; ++m)
#pragma unroll
      for (int n = 0; n < 2; ++n)
#pragma unroll
        for (int q = 0; q < 4; ++q) {
          const int rl = wr * 64 + m * 16 + rbase + q;
          const int cl = wc * 32 + n * 16 + cbase;
          if (rl > cl) fs += acc[m][n][q] * acc[m][n][q];
        }
  }
#pragma unroll
  for (int off = 32; off; off >>= 1) fs += __shfl_down(fs, off);
  if (lane == 0) wred[w] = (double)fs;
  __syncthreads();
  if (tid == 0) {
    double t = 0.0;
#pragma unroll
    for (int i = 0; i < 8; ++i) t += wred[i];
    frobp[b] = t;
  }
}

// ---------------------------------------------------------------------------
// kfinal: fp64 reduce + scalar math.
// ---------------------------------------------------------------------------
__global__ void __launch_bounds__(256) kfinal(const double* __restrict__ rowp,
                                              const double* __restrict__ cssp,
                                              const int* __restrict__ cntp,
                                              const double* __restrict__ frobp,
                                              float* __restrict__ out) {
  __shared__ double red[256];
  const int tid = threadIdx.x;
  double lsum = rowp[tid] + rowp[tid + 256];
  double lcss = 0.0, lcnn = 0.0, lfr = 0.0;
  for (int c = tid; c < N_CLS; c += 256) {
    lcss += cssp[c];
    const double nc = (double)cntp[c];
    lcnn += nc * nc;
  }
  for (int c = tid; c < NBLK; c += 256) lfr += frobp[c];

  double vals[4] = {lsum, lcss, lcnn, lfr};
  double res[4];
  for (int v = 0; v < 4; ++v) {
    red[tid] = vals[v];
    __syncthreads();
    for (int s = 128; s; s >>= 1) {
      if (tid < s) red[tid] += red[tid + s];
      __syncthreads();
    }
    res[v] = red[0];
    __syncthreads();
  }
  if (tid == 0) {
    const double sumr = res[0], css = res[1], cnn = res[2], frob = res[3];
    const double S1 = 0.5 * (css - sumr);
    const double S2 = 0.5 * (cnn - (double)N_ROWS);
    const double S3 = frob;
    out[0] = (float)(-(S1 / (S2 * sqrt(S3))));
  }
}

extern "C" void kernel_launch(void* const* d_in, const int* in_sizes, int n_in,
                              void* d_out, int out_size, void* d_ws, size_t ws_size,
                              hipStream_t stream) {
  const float* A = (const float*)d_in[0];
  const int* target = (const int*)d_in[1];
  float* out = (float*)d_out;

  char* ws = (char*)d_ws;
  short*  Ab    = (short*)ws;                                   // 8,388,608 B
  double* rowp  = (double*)(ws + 8388608);                      // 512 doubles
  double* cssp  = (double*)(ws + 8388608 + 4096);               // 1000 doubles
  int*    cntp  = (int*)   (ws + 8388608 + 4096 + 8000);        // 1000 ints (pad 4096)
  double* frobp = (double*)(ws + 8388608 + 4096 + 8000 + 4096); // 528 doubles

  kconvrow<<<512, 256, 0, stream>>>(A, Ab, rowp);
  kclass<<<N_CLS, 256, 0, stream>>>(A, target, cssp, cntp);
  kfrob<<<NBLK, 512, 0, stream>>>(Ab, frobp);
  kfinal<<<1, 256, 0, stream>>>(rowp, cssp, cntp, frobp, out);
}

// Round 6
// 47.067 us; speedup vs baseline: 1.2222x; 1.0894x over previous
//
#include <hip/hip_runtime.h>
#include <hip/hip_bf16.h>

// AlignmentLoss: loss = -(sum(tril(G,-1)*eq) / (sum(tril(eq,-1)) * ||tril(G,-1)||_F))
// with G = A A^T, A: 4096x1024 fp32, target: 4096 int32 (classes < 1000).
//
//   S1 = 0.5*(sum_c ||s_c||^2 - sum_i ||a_i||^2)   (exact fp32/fp64 path)
//   S2 = 0.5*(sum_c n_c^2 - N)
//   S3 = sum_{i>j} g_ij^2  -- lower-triangle 128x128 tiles of G = A A^T in
//        bf16 MFMA, K=1024 along A's natural layout, fused masked Frobenius.
//   loss = -S1 / (S2 * sqrt(S3))
//
// R6 changes (R5 pipeline kept):
//  1. kfrob XCD swizzle: b = (blk&7)*66 + (blk>>3)  (528 = 8*66, bijective).
//     Co-resident blocks per XCD now share panels -> L3 traffic ~6x down.
//  2. kconvrow + kclass merged into kprep (one launch, class part overlaps
//     the BW-bound convert part; both independent readers of A/target).

typedef __attribute__((ext_vector_type(8))) short short8;
typedef __attribute__((ext_vector_type(4))) float f32x4;

#define N_ROWS 4096
#define D_DIM  1024
#define N_CLS  1000
#define NTILE  32          // 4096 / 128 block-rows
#define NBLK   528         // NTILE*(NTILE+1)/2 lower-triangle tiles
#define NK     32          // 1024 / BK,  BK = 32

__device__ __forceinline__ unsigned short f2bf(float f) {
  unsigned u = __float_as_uint(f);
  u += 0x7fffu + ((u >> 16) & 1u);   // round-to-nearest-even
  return (unsigned short)(u >> 16);
}

__device__ __forceinline__ void gload16(const short* g, const char* l) {
  __builtin_amdgcn_global_load_lds(
      (const __attribute__((address_space(1))) unsigned*)g,
      (__attribute__((address_space(3))) unsigned*)(void*)l, 16, 0, 0);
}

// ---------------------------------------------------------------------------
// kprep: blocks 0..511  = convert A->bf16 + row-norm partials (kconvrow body)
//        blocks 512..   = per-class sum-vector norm + count (kclass body)
// ---------------------------------------------------------------------------
__global__ void __launch_bounds__(256) kprep(const float* __restrict__ A,
                                             const int* __restrict__ target,
                                             short* __restrict__ Ab,
                                             double* __restrict__ rowp,
                                             double* __restrict__ cssp,
                                             int* __restrict__ cntp) {
  const int tid = threadIdx.x, lane = tid & 63, w = tid >> 6;

  if (blockIdx.x < 512) {
    // ---- convert + row norms ----
    __shared__ double wr2[4];
    const int row0 = blockIdx.x * 8;
    double ls = 0.0;
#pragma unroll
    for (int rr = 0; rr < 2; ++rr) {
      const int i = row0 + w * 2 + rr;
      const float4* src = (const float4*)(A + (size_t)i * D_DIM);
      short4* dst = (short4*)(Ab + (size_t)i * D_DIM);
      float s = 0.f;
#pragma unroll
      for (int c = 0; c < 4; ++c) {
        const float4 v = src[lane + c * 64];
        s += v.x * v.x + v.y * v.y + v.z * v.z + v.w * v.w;
        short4 o;
        o.x = (short)f2bf(v.x); o.y = (short)f2bf(v.y);
        o.z = (short)f2bf(v.z); o.w = (short)f2bf(v.w);
        dst[lane + c * 64] = o;
      }
#pragma unroll
      for (int off = 32; off; off >>= 1) s += __shfl_down(s, off);
      if (lane == 0) ls += (double)s;
    }
    if (lane == 0) wr2[w] = ls;
    __syncthreads();
    if (tid == 0) rowp[blockIdx.x] = wr2[0] + wr2[1] + wr2[2] + wr2[3];
  } else {
    // ---- per-class reduction ----
    __shared__ int list[N_ROWS];
    __shared__ int lcnt;
    __shared__ float wred[4];
    const int c = blockIdx.x - 512;
    if (c >= N_CLS) return;
    if (tid == 0) lcnt = 0;
    __syncthreads();
    for (int j = tid; j < N_ROWS; j += 256)
      if (target[j] == c) { int p = atomicAdd(&lcnt, 1); list[p] = j; }
    __syncthreads();
    const int n = lcnt;
    float4 acc = make_float4(0.f, 0.f, 0.f, 0.f);
    for (int m = 0; m < n; ++m) {
      const float4 v = *(const float4*)(A + (size_t)list[m] * D_DIM + tid * 4);
      acc.x += v.x; acc.y += v.y; acc.z += v.z; acc.w += v.w;
    }
    float s = acc.x * acc.x + acc.y * acc.y + acc.z * acc.z + acc.w * acc.w;
#pragma unroll
    for (int off = 32; off; off >>= 1) s += __shfl_down(s, off);
    if (lane == 0) wred[w] = s;
    __syncthreads();
    if (tid == 0) {
      cssp[c] = (double)(wred[0] + wred[1] + wred[2] + wred[3]);
      cntp[c] = n;
    }
  }
}

// ---------------------------------------------------------------------------
// kfrob: lower-triangle 128x128 tiles of G = Ab*Ab^T, bf16 MFMA, 8 waves
// (2x4, 64x32 per wave), LDS double-buffer + counted-vmcnt pipeline, fused
// masked Frobenius.  Grid NBLK=528 x 512 threads.  XCD-swizzled block map.
// ---------------------------------------------------------------------------
__global__ void __launch_bounds__(512, 4) kfrob(const short* __restrict__ Ab,
                                                double* __restrict__ frobp) {
  __shared__ __align__(16) short As[2][128 * 32];   // 2 x 8 KB
  __shared__ __align__(16) short Bs[2][128 * 32];   // 2 x 8 KB
  __shared__ double wred[8];
  const int tid = threadIdx.x, lane = tid & 63, w = tid >> 6;

  // XCD-aware swizzle: 528 = 8 * 66; XCD x gets contiguous triangle chunk.
  const int b = (blockIdx.x & 7) * 66 + (blockIdx.x >> 3);

  // decode lower-triangle pair: b = bi*(bi+1)/2 + bj, bj <= bi
  int bi = (int)((sqrtf(8.f * (float)b + 1.f) - 1.f) * 0.5f);
  while ((bi + 1) * (bi + 2) / 2 <= b) ++bi;
  while (bi * (bi + 1) / 2 > b) --bi;
  const int bj = b - bi * (bi + 1) / 2;
  const bool diag = (bi == bj);

  const short* Pa = Ab + (size_t)(bi * 128) * D_DIM;
  const short* Pb = Ab + (size_t)(bj * 128) * D_DIM;

  f32x4 acc[4][2];
#pragma unroll
  for (int m = 0; m < 4; ++m)
#pragma unroll
    for (int n = 0; n < 2; ++n) acc[m][n] = (f32x4){0.f, 0.f, 0.f, 0.f};

  const int wr = w >> 2, wc = w & 3;             // wave tile: rows 64*wr, cols 32*wc
  const int row16 = lane & 15, ko = (lane >> 4) * 8;

  // staging: 512 thr x 16B = 8KB = one full [128][32]-short buffer per issue.
  const int sr = tid >> 2, sc = tid & 3;
  const size_t gofs = (size_t)sr * D_DIM + sc * 8;
  const int lofs = w * 1024;                     // = tid*16 - lane*16 (linear)

#define STAGE(buf, k0)                                                      \
  do {                                                                      \
    gload16(Pa + gofs + (k0), (const char*)As[buf] + lofs);                 \
    gload16(Pb + gofs + (k0), (const char*)Bs[buf] + lofs);                 \
  } while (0)

#define COMPUTE(buf)                                                        \
  do {                                                                      \
    short8 af[4], bf[2];                                                    \
    _Pragma("unroll")                                                       \
    for (int m = 0; m < 4; ++m)                                             \
      af[m] = *(const short8*)&As[buf][(wr * 64 + m * 16 + row16) * 32 + ko];\
    _Pragma("unroll")                                                       \
    for (int n = 0; n < 2; ++n)                                             \
      bf[n] = *(const short8*)&Bs[buf][(wc * 32 + n * 16 + row16) * 32 + ko];\
    _Pragma("unroll")                                                       \
    for (int m = 0; m < 4; ++m)                                             \
      _Pragma("unroll")                                                     \
      for (int n = 0; n < 2; ++n)                                           \
        acc[m][n] = __builtin_amdgcn_mfma_f32_16x16x32_bf16(af[m], bf[n],   \
                                                            acc[m][n], 0, 0, 0);\
  } while (0)

  STAGE(0, 0);                       // prologue: tile 0 in flight
  int cur = 0;
#pragma unroll 1
  for (int t = 0; t < NK - 1; ++t) {
    STAGE(cur ^ 1, (t + 1) * 32);    // issue next tile (2 loads/thread)
    asm volatile("s_waitcnt vmcnt(2)" ::: "memory");   // wait tile t only
    __builtin_amdgcn_sched_barrier(0);
    __builtin_amdgcn_s_barrier();    // all waves: tile t resident
    __builtin_amdgcn_sched_barrier(0);
    COMPUTE(cur);
    asm volatile("s_waitcnt lgkmcnt(0)" ::: "memory"); // all ds_reads retired
    __builtin_amdgcn_sched_barrier(0);
    __builtin_amdgcn_s_barrier();    // safe to overwrite buf cur next iter
    __builtin_amdgcn_sched_barrier(0);
    cur ^= 1;
  }
  asm volatile("s_waitcnt vmcnt(0)" ::: "memory");     // last tile resident
  __builtin_amdgcn_sched_barrier(0);
  __builtin_amdgcn_s_barrier();
  __builtin_amdgcn_sched_barrier(0);
  COMPUTE(cur);
#undef STAGE
#undef COMPUTE

  float fs = 0.f;
  if (!diag) {
#pragma unroll
    for (int m = 0; m < 4; ++m)
#pragma unroll
      for (int n = 0; n < 2; ++n)
#pragma unroll
        for (int q = 0; q < 4; ++q) fs += acc[m][n][q] * acc[m][n][q];
  } else {
    const int rbase = (lane >> 4) * 4, cbase = lane & 15;
#pragma unroll
    for (int m = 0; m < 4; ++m)
#pragma unroll
      for (int n = 0; n < 2; ++n)
#pragma unroll
        for (int q = 0; q < 4; ++q) {
          const int rl = wr * 64 + m * 16 + rbase + q;
          const int cl = wc * 32 + n * 16 + cbase;
          if (rl > cl) fs += acc[m][n][q] * acc[m][n][q];
        }
  }
#pragma unroll
  for (int off = 32; off; off >>= 1) fs += __shfl_down(fs, off);
  if (lane == 0) wred[w] = (double)fs;
  __syncthreads();
  if (tid == 0) {
    double t = 0.0;
#pragma unroll
    for (int i = 0; i < 8; ++i) t += wred[i];
    frobp[b] = t;
  }
}

// ---------------------------------------------------------------------------
// kfinal: fp64 reduce + scalar math.
// ---------------------------------------------------------------------------
__global__ void __launch_bounds__(256) kfinal(const double* __restrict__ rowp,
                                              const double* __restrict__ cssp,
                                              const int* __restrict__ cntp,
                                              const double* __restrict__ frobp,
                                              float* __restrict__ out) {
  __shared__ double red[256];
  const int tid = threadIdx.x;
  double lsum = rowp[tid] + rowp[tid + 256];
  double lcss = 0.0, lcnn = 0.0, lfr = 0.0;
  for (int c = tid; c < N_CLS; c += 256) {
    lcss += cssp[c];
    const double nc = (double)cntp[c];
    lcnn += nc * nc;
  }
  for (int c = tid; c < NBLK; c += 256) lfr += frobp[c];

  double vals[4] = {lsum, lcss, lcnn, lfr};
  double res[4];
  for (int v = 0; v < 4; ++v) {
    red[tid] = vals[v];
    __syncthreads();
    for (int s = 128; s; s >>= 1) {
      if (tid < s) red[tid] += red[tid + s];
      __syncthreads();
    }
    res[v] = red[0];
    __syncthreads();
  }
  if (tid == 0) {
    const double sumr = res[0], css = res[1], cnn = res[2], frob = res[3];
    const double S1 = 0.5 * (css - sumr);
    const double S2 = 0.5 * (cnn - (double)N_ROWS);
    const double S3 = frob;
    out[0] = (float)(-(S1 / (S2 * sqrt(S3))));
  }
}

extern "C" void kernel_launch(void* const* d_in, const int* in_sizes, int n_in,
                              void* d_out, int out_size, void* d_ws, size_t ws_size,
                              hipStream_t stream) {
  const float* A = (const float*)d_in[0];
  const int* target = (const int*)d_in[1];
  float* out = (float*)d_out;

  char* ws = (char*)d_ws;
  short*  Ab    = (short*)ws;                                   // 8,388,608 B
  double* rowp  = (double*)(ws + 8388608);                      // 512 doubles
  double* cssp  = (double*)(ws + 8388608 + 4096);               // 1000 doubles
  int*    cntp  = (int*)   (ws + 8388608 + 4096 + 8000);        // 1000 ints (pad 4096)
  double* frobp = (double*)(ws + 8388608 + 4096 + 8000 + 4096); // 528 doubles

  kprep<<<512 + N_CLS, 256, 0, stream>>>(A, target, Ab, rowp, cssp, cntp);
  kfrob<<<NBLK, 512, 0, stream>>>(Ab, frobp);
  kfinal<<<1, 256, 0, stream>>>(rowp, cssp, cntp, frobp, out);
}

// Round 7
// 45.966 us; speedup vs baseline: 1.2515x; 1.0240x over previous
//
#include <hip/hip_runtime.h>
#include <hip/hip_bf16.h>

// AlignmentLoss: loss = -(sum(tril(G,-1)*eq) / (sum(tril(eq,-1)) * ||tril(G,-1)||_F))
// with G = A A^T, A: 4096x1024 fp32, target: 4096 int32 (classes < 1000).
//
//   S1 = 0.5*(sum_c ||s_c||^2 - sum_i ||a_i||^2)   (exact fp32/fp64 path)
//   S2 = 0.5*(sum_c n_c^2 - N)
//   S3 = sum_{i>j} g_ij^2  -- lower-triangle 128x128 tiles of G = A A^T in
//        bf16 MFMA, K=1024 along A's natural layout, fused masked Frobenius.
//   loss = -S1 / (S2 * sqrt(S3))
//
// R7 change (isolated vs R6): LDS bank-conflict fix in kfrob.  The [128][32]
// short tile has 64-B row stride -> 16 lanes reading rows 0..15 at one 16-B
// chunk hit 2 bank-quads = 8-way conflict (R1 measured 1M conflict cycles =
// +16 cy/read).  Fix per rule #21 (both-sides-or-neither with global_load_lds):
// LDS stays linear; the GLOBAL source chunk is pre-swizzled by
// chunk ^= (row>>1)&3 and the ds_read applies the same XOR -> rows 0..15
// spread over 8 slots x 2 rows = 2-way (free).

typedef __attribute__((ext_vector_type(8))) short short8;
typedef __attribute__((ext_vector_type(4))) float f32x4;

#define N_ROWS 4096
#define D_DIM  1024
#define N_CLS  1000
#define NTILE  32          // 4096 / 128 block-rows
#define NBLK   528         // NTILE*(NTILE+1)/2 lower-triangle tiles
#define NK     32          // 1024 / BK,  BK = 32

__device__ __forceinline__ unsigned short f2bf(float f) {
  unsigned u = __float_as_uint(f);
  u += 0x7fffu + ((u >> 16) & 1u);   // round-to-nearest-even
  return (unsigned short)(u >> 16);
}

__device__ __forceinline__ void gload16(const short* g, const char* l) {
  __builtin_amdgcn_global_load_lds(
      (const __attribute__((address_space(1))) unsigned*)g,
      (__attribute__((address_space(3))) unsigned*)(void*)l, 16, 0, 0);
}

// ---------------------------------------------------------------------------
// kprep: blocks 0..511  = convert A->bf16 + row-norm partials
//        blocks 512..   = per-class sum-vector norm + count
// ---------------------------------------------------------------------------
__global__ void __launch_bounds__(256) kprep(const float* __restrict__ A,
                                             const int* __restrict__ target,
                                             short* __restrict__ Ab,
                                             double* __restrict__ rowp,
                                             double* __restrict__ cssp,
                                             int* __restrict__ cntp) {
  const int tid = threadIdx.x, lane = tid & 63, w = tid >> 6;

  if (blockIdx.x < 512) {
    __shared__ double wr2[4];
    const int row0 = blockIdx.x * 8;
    double ls = 0.0;
#pragma unroll
    for (int rr = 0; rr < 2; ++rr) {
      const int i = row0 + w * 2 + rr;
      const float4* src = (const float4*)(A + (size_t)i * D_DIM);
      short4* dst = (short4*)(Ab + (size_t)i * D_DIM);
      float s = 0.f;
#pragma unroll
      for (int c = 0; c < 4; ++c) {
        const float4 v = src[lane + c * 64];
        s += v.x * v.x + v.y * v.y + v.z * v.z + v.w * v.w;
        short4 o;
        o.x = (short)f2bf(v.x); o.y = (short)f2bf(v.y);
        o.z = (short)f2bf(v.z); o.w = (short)f2bf(v.w);
        dst[lane + c * 64] = o;
      }
#pragma unroll
      for (int off = 32; off; off >>= 1) s += __shfl_down(s, off);
      if (lane == 0) ls += (double)s;
    }
    if (lane == 0) wr2[w] = ls;
    __syncthreads();
    if (tid == 0) rowp[blockIdx.x] = wr2[0] + wr2[1] + wr2[2] + wr2[3];
  } else {
    __shared__ int list[N_ROWS];
    __shared__ int lcnt;
    __shared__ float wred[4];
    const int c = blockIdx.x - 512;
    if (c >= N_CLS) return;
    if (tid == 0) lcnt = 0;
    __syncthreads();
    for (int j = tid; j < N_ROWS; j += 256)
      if (target[j] == c) { int p = atomicAdd(&lcnt, 1); list[p] = j; }
    __syncthreads();
    const int n = lcnt;
    float4 acc = make_float4(0.f, 0.f, 0.f, 0.f);
    for (int m = 0; m < n; ++m) {
      const float4 v = *(const float4*)(A + (size_t)list[m] * D_DIM + tid * 4);
      acc.x += v.x; acc.y += v.y; acc.z += v.z; acc.w += v.w;
    }
    float s = acc.x * acc.x + acc.y * acc.y + acc.z * acc.z + acc.w * acc.w;
#pragma unroll
    for (int off = 32; off; off >>= 1) s += __shfl_down(s, off);
    if (lane == 0) wred[w] = s;
    __syncthreads();
    if (tid == 0) {
      cssp[c] = (double)(wred[0] + wred[1] + wred[2] + wred[3]);
      cntp[c] = n;
    }
  }
}

// ---------------------------------------------------------------------------
// kfrob: lower-triangle 128x128 tiles of G = Ab*Ab^T, bf16 MFMA, 8 waves
// (2x4, 64x32 per wave), dbuf + counted-vmcnt pipeline, bank-swizzled LDS,
// fused masked Frobenius.  Grid NBLK=528 x 512 threads.  XCD-swizzled map.
// ---------------------------------------------------------------------------
__global__ void __launch_bounds__(512, 4) kfrob(const short* __restrict__ Ab,
                                                double* __restrict__ frobp) {
  __shared__ __align__(16) short As[2][128 * 32];   // 2 x 8 KB
  __shared__ __align__(16) short Bs[2][128 * 32];   // 2 x 8 KB
  __shared__ double wred[8];
  const int tid = threadIdx.x, lane = tid & 63, w = tid >> 6;

  // XCD-aware swizzle: 528 = 8 * 66; XCD x gets contiguous triangle chunk.
  const int b = (blockIdx.x & 7) * 66 + (blockIdx.x >> 3);

  // decode lower-triangle pair: b = bi*(bi+1)/2 + bj, bj <= bi
  int bi = (int)((sqrtf(8.f * (float)b + 1.f) - 1.f) * 0.5f);
  while ((bi + 1) * (bi + 2) / 2 <= b) ++bi;
  while (bi * (bi + 1) / 2 > b) --bi;
  const int bj = b - bi * (bi + 1) / 2;
  const bool diag = (bi == bj);

  const short* Pa = Ab + (size_t)(bi * 128) * D_DIM;
  const short* Pb = Ab + (size_t)(bj * 128) * D_DIM;

  f32x4 acc[4][2];
#pragma unroll
  for (int m = 0; m < 4; ++m)
#pragma unroll
    for (int n = 0; n < 2; ++n) acc[m][n] = (f32x4){0.f, 0.f, 0.f, 0.f};

  const int wr = w >> 2, wc = w & 3;             // wave tile: rows 64*wr, cols 32*wc
  const int row16 = lane & 15, ck = lane >> 4;   // ck = 16-B chunk index 0..3

  // staging: 512 thr x 16B = one full [128][32]-short buffer per issue.
  // Source chunk pre-swizzled so LDS[row][c] = G[row][c ^ ((row>>1)&3)]^-1:
  // thread (sr,sc) loads global chunk sc ^ ((sr>>1)&3), writes linear t*16.
  const int sr = tid >> 2, sc = tid & 3;
  const int scS = sc ^ ((sr >> 1) & 3);
  const size_t gofs = (size_t)sr * D_DIM + scS * 8;
  const int lofs = w * 1024;                     // = tid*16 - lane*16 (linear)

#define STAGE(buf, k0)                                                      \
  do {                                                                      \
    gload16(Pa + gofs + (k0), (const char*)As[buf] + lofs);                 \
    gload16(Pb + gofs + (k0), (const char*)Bs[buf] + lofs);                 \
  } while (0)

  // swizzled ds_read offset (in shorts) for row R, chunk ck
#define SWZ(R) (((R) * 32) + ((ck ^ (((R) >> 1) & 3)) * 8))

#define COMPUTE(buf)                                                        \
  do {                                                                      \
    short8 af[4], bf[2];                                                    \
    _Pragma("unroll")                                                       \
    for (int m = 0; m < 4; ++m)                                             \
      af[m] = *(const short8*)&As[buf][SWZ(wr * 64 + m * 16 + row16)];      \
    _Pragma("unroll")                                                       \
    for (int n = 0; n < 2; ++n)                                             \
      bf[n] = *(const short8*)&Bs[buf][SWZ(wc * 32 + n * 16 + row16)];      \
    _Pragma("unroll")                                                       \
    for (int m = 0; m < 4; ++m)                                             \
      _Pragma("unroll")                                                     \
      for (int n = 0; n < 2; ++n)                                           \
        acc[m][n] = __builtin_amdgcn_mfma_f32_16x16x32_bf16(af[m], bf[n],   \
                                                            acc[m][n], 0, 0, 0);\
  } while (0)

  STAGE(0, 0);                       // prologue: tile 0 in flight
  int cur = 0;
#pragma unroll 1
  for (int t = 0; t < NK - 1; ++t) {
    STAGE(cur ^ 1, (t + 1) * 32);    // issue next tile (2 loads/thread)
    asm volatile("s_waitcnt vmcnt(2)" ::: "memory");   // wait tile t only
    __builtin_amdgcn_sched_barrier(0);
    __builtin_amdgcn_s_barrier();    // all waves: tile t resident
    __builtin_amdgcn_sched_barrier(0);
    COMPUTE(cur);
    asm volatile("s_waitcnt lgkmcnt(0)" ::: "memory"); // all ds_reads retired
    __builtin_amdgcn_sched_barrier(0);
    __builtin_amdgcn_s_barrier();    // safe to overwrite buf cur next iter
    __builtin_amdgcn_sched_barrier(0);
    cur ^= 1;
  }
  asm volatile("s_waitcnt vmcnt(0)" ::: "memory");     // last tile resident
  __builtin_amdgcn_sched_barrier(0);
  __builtin_amdgcn_s_barrier();
  __builtin_amdgcn_sched_barrier(0);
  COMPUTE(cur);
#undef STAGE
#undef COMPUTE
#undef SWZ

  float fs = 0.f;
  if (!diag) {
#pragma unroll
    for (int m = 0; m < 4; ++m)
#pragma unroll
      for (int n = 0; n < 2; ++n)
#pragma unroll
        for (int q = 0; q < 4; ++q) fs += acc[m][n][q] * acc[m][n][q];
  } else {
    const int rbase = (lane >> 4) * 4, cbase = lane & 15;
#pragma unroll
    for (int m = 0; m < 4; ++m)
#pragma unroll
      for (int n = 0; n < 2; ++n)
#pragma unroll
        for (int q = 0; q < 4; ++q) {
          const int rl = wr * 64 + m * 16 + rbase + q;
          const int cl = wc * 32 + n * 16 + cbase;
          if (rl > cl) fs += acc[m][n][q] * acc[m][n][q];
        }
  }
#pragma unroll
  for (int off = 32; off; off >>= 1) fs += __shfl_down(fs, off);
  if (lane == 0) wred[w] = (double)fs;
  __syncthreads();
  if (tid == 0) {
    double t = 0.0;
#pragma unroll
    for (int i = 0; i < 8; ++i) t += wred[i];
    frobp[b] = t;
  }
}

// ---------------------------------------------------------------------------
// kfinal: fp64 reduce + scalar math.
// ---------------------------------------------------------------------------
__global__ void __launch_bounds__(256) kfinal(const double* __restrict__ rowp,
                                              const double* __restrict__ cssp,
                                              const int* __restrict__ cntp,
                                              const double* __restrict__ frobp,
                                              float* __restrict__ out) {
  __shared__ double red[256];
  const int tid = threadIdx.x;
  double lsum = rowp[tid] + rowp[tid + 256];
  double lcss = 0.0, lcnn = 0.0, lfr = 0.0;
  for (int c = tid; c < N_CLS; c += 256) {
    lcss += cssp[c];
    const double nc = (double)cntp[c];
    lcnn += nc * nc;
  }
  for (int c = tid; c < NBLK; c += 256) lfr += frobp[c];

  double vals[4] = {lsum, lcss, lcnn, lfr};
  double res[4];
  for (int v = 0; v < 4; ++v) {
    red[tid] = vals[v];
    __syncthreads();
    for (int s = 128; s; s >>= 1) {
      if (tid < s) red[tid] += red[tid + s];
      __syncthreads();
    }
    res[v] = red[0];
    __syncthreads();
  }
  if (tid == 0) {
    const double sumr = res[0], css = res[1], cnn = res[2], frob = res[3];
    const double S1 = 0.5 * (css - sumr);
    const double S2 = 0.5 * (cnn - (double)N_ROWS);
    const double S3 = frob;
    out[0] = (float)(-(S1 / (S2 * sqrt(S3))));
  }
}

extern "C" void kernel_launch(void* const* d_in, const int* in_sizes, int n_in,
                              void* d_out, int out_size, void* d_ws, size_t ws_size,
                              hipStream_t stream) {
  const float* A = (const float*)d_in[0];
  const int* target = (const int*)d_in[1];
  float* out = (float*)d_out;

  char* ws = (char*)d_ws;
  short*  Ab    = (short*)ws;                                   // 8,388,608 B
  double* rowp  = (double*)(ws + 8388608);                      // 512 doubles
  double* cssp  = (double*)(ws + 8388608 + 4096);               // 1000 doubles
  int*    cntp  = (int*)   (ws + 8388608 + 4096 + 8000);        // 1000 ints (pad 4096)
  double* frobp = (double*)(ws + 8388608 + 4096 + 8000 + 4096); // 528 doubles

  kprep<<<512 + N_CLS, 256, 0, stream>>>(A, target, Ab, rowp, cssp, cntp);
  kfrob<<<NBLK, 512, 0, stream>>>(Ab, frobp);
  kfinal<<<1, 256, 0, stream>>>(rowp, cssp, cntp, frobp, out);
}